// Round 6
// baseline (512.553 us; speedup 1.0000x reference)
//
#include <hip/hip_runtime.h>
#include <cstdint>

#define NN 20000
#define NNP 20096            // 157 * 128, padded row count for all activation buffers
#define NE 640000
#define NEG_SLOPE 0.1f
#define NSCAN 79             // ceil(NN/256)
#define NSL 8                // dst slices (XCD-count)
#define NPSL 2500            // nodes per slice
#define FBPS 160             // fill blocks per slice

typedef unsigned short ushort_t;
typedef __attribute__((ext_vector_type(8))) short short8;
typedef __attribute__((ext_vector_type(4))) float f32x4;
typedef __attribute__((ext_vector_type(2))) float f32x2;

__device__ __forceinline__ unsigned short f2bf(float f) {
    union { float f; unsigned u; } v; v.f = f;
    unsigned r = v.u + 0x7fffu + ((v.u >> 16) & 1u);
    return (unsigned short)(r >> 16);
}
__device__ __forceinline__ float bflo(unsigned u) { return __uint_as_float(u << 16); }
__device__ __forceinline__ float bfhi(unsigned u) { return __uint_as_float(u & 0xffff0000u); }

__device__ __forceinline__ int swz(int r) { return (r ^ (r >> 2)) & 3; }

__device__ __forceinline__ void gld_lds16(const void* g, void* l) {
    __builtin_amdgcn_global_load_lds(
        (const __attribute__((address_space(1))) void*)g,
        (__attribute__((address_space(3))) void*)l,
        16, 0, 0);
}

// ---------------- packed Wt region offsets (elements, bf16) ----------------
// All Wt stored as [M][K] row-major (transposed from source [K][M])
#define O_CAT   0            // 384 x 736
#define O_OM    282624       // 384 x 64 (K padded 54->64 with zeros)
#define O_C0    307200       // 128 x 384
#define O_O0    356352       // 128 x 384
#define O_C1    405504       // 128 x 128
#define O_O1    421888
#define O_C2    438272
#define O_O2    454656
#define O_LAT   471040       // 384 x 768
#define O_HEADS 765952       // 256 x 384  (rows 0..127 = drug, 128..255 = dis)
#define WT_TOTAL 864256

__global__ __launch_bounds__(256) void pack_weights(
    const float* __restrict__ Wpe, const float* __restrict__ Wgos, const float* __restrict__ Wprot,
    const float* __restrict__ bpe, const float* __restrict__ bgos, const float* __restrict__ bprot,
    const float* __restrict__ Wom0, const float* __restrict__ Wom1,
    const float* __restrict__ Wom2, const float* __restrict__ Wom3,
    const float* __restrict__ bom0, const float* __restrict__ bom1,
    const float* __restrict__ bom2, const float* __restrict__ bom3,
    const float* __restrict__ Wc0, const float* __restrict__ Wo0,
    const float* __restrict__ Wc1, const float* __restrict__ Wo1,
    const float* __restrict__ Wc2, const float* __restrict__ Wo2,
    const float* __restrict__ Wlat,
    const float* __restrict__ Wdrug, const float* __restrict__ Wdis,
    const float* __restrict__ bdrug, const float* __restrict__ bdis,
    ushort_t* __restrict__ Wt, float* __restrict__ bcat, float* __restrict__ bomc,
    float* __restrict__ bheads)
{
    int i = blockIdx.x * blockDim.x + threadIdx.x;
    if (i < 282624) {                            // WtCat 384 x 736
        int m = i / 736, k = i % 736;
        float v = (k < 128) ? Wpe[k * 384 + m]
                : (k < 256) ? Wgos[(k - 128) * 384 + m]
                            : Wprot[(k - 256) * 384 + m];
        Wt[O_CAT + i] = f2bf(v);
        return;
    }
    i -= 282624;
    if (i < 24576) {                             // WtOm 384 x 64
        int m = i / 64, k = i % 64;
        float v = (k < 3)  ? Wom0[k * 384 + m]
                : (k < 6)  ? Wom1[(k - 3) * 384 + m]
                : (k < 30) ? Wom2[(k - 6) * 384 + m]
                : (k < 54) ? Wom3[(k - 30) * 384 + m] : 0.f;
        Wt[O_OM + i] = f2bf(v);
        return;
    }
    i -= 24576;
    if (i < 49152) { int m = i / 384, k = i % 384; Wt[O_C0 + i] = f2bf(Wc0[k * 128 + m]); return; }
    i -= 49152;
    if (i < 49152) { int m = i / 384, k = i % 384; Wt[O_O0 + i] = f2bf(Wo0[k * 128 + m]); return; }
    i -= 49152;
    if (i < 16384) { int m = i / 128, k = i % 128; Wt[O_C1 + i] = f2bf(Wc1[k * 128 + m]); return; }
    i -= 16384;
    if (i < 16384) { int m = i / 128, k = i % 128; Wt[O_O1 + i] = f2bf(Wo1[k * 128 + m]); return; }
    i -= 16384;
    if (i < 16384) { int m = i / 128, k = i % 128; Wt[O_C2 + i] = f2bf(Wc2[k * 128 + m]); return; }
    i -= 16384;
    if (i < 16384) { int m = i / 128, k = i % 128; Wt[O_O2 + i] = f2bf(Wo2[k * 128 + m]); return; }
    i -= 16384;
    if (i < 294912) { int m = i / 768, k = i % 768; Wt[O_LAT + i] = f2bf(Wlat[k * 384 + m]); return; }
    i -= 294912;
    if (i < 98304) {                             // heads 256 x 384
        int m = i / 384, k = i % 384;
        float v = (m < 128) ? Wdrug[k * 128 + m] : Wdis[k * 128 + (m - 128)];
        Wt[O_HEADS + i] = f2bf(v);
        return;
    }
    i -= 98304;
    if (i < 384) { bcat[i] = bpe[i] + bgos[i] + bprot[i]; return; }
    i -= 384;
    if (i < 384) { bomc[i] = bom0[i] + bom1[i] + bom2[i] + bom3[i]; return; }
    i -= 384;
    if (i < 256) { bheads[i] = (i < 128) ? bdrug[i] : bdis[i - 128]; return; }
}

// ---------------- fused input conversion ----------------
#define CVT_T1 (NN * 736 / 4)
__global__ __launch_bounds__(256) void convert_inputs(
    const float* __restrict__ x, const float* __restrict__ xft,
    ushort_t* __restrict__ xb, ushort_t* __restrict__ xftb)
{
    int i = blockIdx.x * blockDim.x + threadIdx.x;
    if (i < CVT_T1) {
        int base = i * 4;
        float4 v = *reinterpret_cast<const float4*>(&x[base]);
        unsigned long long p = (unsigned long long)f2bf(v.x)
                             | ((unsigned long long)f2bf(v.y) << 16)
                             | ((unsigned long long)f2bf(v.z) << 32)
                             | ((unsigned long long)f2bf(v.w) << 48);
        *reinterpret_cast<unsigned long long*>(&xb[base]) = p;
        return;
    }
    i -= CVT_T1;
    if (i < NN * 64) {
        int r = i >> 6, c = i & 63;
        float v = (c < 54) ? xft[r * 54 + c] : 0.f;
        xftb[i] = f2bf(v);
    }
}

// ---------------- degree / CSR (sliced: slice = blockIdx.x & 7 owns 2500 dsts) ----
__global__ __launch_bounds__(256) void count_deg_sliced(const int* __restrict__ dst, int* __restrict__ cnt)
{
    const int slice = blockIdx.x & (NSL - 1);
    const int blk = blockIdx.x >> 3;
    const int lo = slice * NPSL, hi = lo + NPSL;
    for (int e = blk * 256 + threadIdx.x; e < NE; e += FBPS * 256) {
        int d = dst[e];
        if (d >= lo && d < hi) atomicAdd(&cnt[d], 1);
    }
}

// hierarchical scan: per-block sums (+deg_inv) -> tiny top scan -> apply
__global__ __launch_bounds__(256) void scan_blocksums(const int* __restrict__ cnt, int* __restrict__ bsum,
                                                      float* __restrict__ deg_inv)
{
    __shared__ int s[256];
    int t = threadIdx.x, i = blockIdx.x * 256 + t;
    int v = (i < NN) ? cnt[i] : 0;
    if (i < NN) deg_inv[i] = rsqrtf((float)v + 2.0f);
    s[t] = v;
    __syncthreads();
    for (int off = 128; off; off >>= 1) {
        if (t < off) s[t] += s[t + off];
        __syncthreads();
    }
    if (t == 0) bsum[blockIdx.x] = s[0];
}

__global__ __launch_bounds__(128) void scan_tops(const int* __restrict__ bsum,
                                                 int* __restrict__ boff, int* __restrict__ ofs)
{
    __shared__ int s[NSCAN];
    int t = threadIdx.x;
    if (t < NSCAN) s[t] = bsum[t];
    __syncthreads();
    if (t == 0) {
        int run = 0;
        for (int b = 0; b < NSCAN; b++) { int x = s[b]; s[b] = run; run += x; }
        ofs[NN] = run;
    }
    __syncthreads();
    if (t < NSCAN) boff[t] = s[t];
}

__global__ __launch_bounds__(256) void scan_apply(const int* __restrict__ cnt, const int* __restrict__ boff,
                                                  int* __restrict__ ofs, int* __restrict__ cursor)
{
    __shared__ int s[256];
    int t = threadIdx.x, i = blockIdx.x * 256 + t;
    int v = (i < NN) ? cnt[i] : 0;
    s[t] = v;
    __syncthreads();
    for (int off = 1; off < 256; off <<= 1) {
        int u = (t >= off) ? s[t - off] : 0;
        __syncthreads();
        s[t] += u;
        __syncthreads();
    }
    int excl = s[t] - v + boff[blockIdx.x];
    if (i < NN) { ofs[i] = excl; cursor[i] = excl; }
}

// sliced fill: per-slice cursor atomics hit a 10 KB region; csr writes land in a
// contiguous ~640 KB per-slice region. Packed entry: x = src*256 (byte offset of
// the 128-feat bf16 table row), y = coefficient fp32 bits.
__global__ __launch_bounds__(256) void fill_csr_sliced(
    const int* __restrict__ src, const int* __restrict__ dst,
    const float* __restrict__ deg_inv, int* __restrict__ cursor,
    uint2* __restrict__ csr_pk)
{
    const int slice = blockIdx.x & (NSL - 1);
    const int blk = blockIdx.x >> 3;
    const int lo = slice * NPSL, hi = lo + NPSL;
    for (int e = blk * 256 + threadIdx.x; e < NE; e += FBPS * 256) {
        int d = dst[e];
        if (d >= lo && d < hi) {
            int s = src[e];
            int p = atomicAdd(&cursor[d], 1);
            float cf = deg_inv[s] * deg_inv[d];
            csr_pk[p] = make_uint2((unsigned)s * 256u, __float_as_uint(cf));
        }
    }
}

// ---------------- bf16 MFMA GEMM body ----------------
// C[nrows x M] = [act]( A(bf16, nrows x K, lda) @ Wt(bf16, [M][K])^T [+ bias] )
// BM=128, BK=32, 256 threads = 4 waves 2x2. A buffers must have >= gridDim.y*128 rows.
template<int BN, bool BIASACT, bool OUT_BF16>
__device__ __forceinline__ void gemm_body(
    ushort_t* As, ushort_t* Bs,
    const ushort_t* __restrict__ A, int lda,
    const ushort_t* __restrict__ Wt,
    const float* __restrict__ bias,
    float* __restrict__ Cf, ushort_t* __restrict__ Cb, int ldc,
    int nrows, int K, int row0, int col0)
{
    constexpr int BK = 32;
    constexpr int NI = (BN == 128) ? 4 : 2;

    const int t = threadIdx.x;
    const int w = t >> 6, lane = t & 63;
    const int wr = w >> 1, wc = w & 1;
    const int m16 = lane & 15, quad = lane >> 4;
    const int sr = lane >> 2;       // row within a 16-row staging chunk
    const int pgrp = lane & 3;      // physical 16B group within row

    f32x4 acc[4][NI];
#pragma unroll
    for (int mi = 0; mi < 4; mi++)
#pragma unroll
        for (int ni = 0; ni < NI; ni++) acc[mi][ni] = (f32x4)0.f;

    for (int k0 = 0; k0 < K; k0 += BK) {
#pragma unroll
        for (int p = 0; p < 2; p++) {
            int c = p * 4 + w;
            int r = c * 16 + sr;
            int q = pgrp ^ swz(r);
            gld_lds16(&A[(size_t)(row0 + r) * lda + k0 + q * 8], &As[c * 512]);
        }
#pragma unroll
        for (int p = 0; p < BN / 64; p++) {
            int c = p * 4 + w;
            int r = c * 16 + sr;
            int q = pgrp ^ swz(r);
            gld_lds16(&Wt[(size_t)(col0 + r) * K + k0 + q * 8], &Bs[c * 512]);
        }
        __syncthreads();

        short8 af[4], bfr[NI];
#pragma unroll
        for (int mi = 0; mi < 4; mi++) {
            int r = wr * 64 + mi * 16 + m16;
            int p = quad ^ swz(r);
            af[mi] = *reinterpret_cast<const short8*>(&As[r * 32 + p * 8]);
        }
#pragma unroll
        for (int ni = 0; ni < NI; ni++) {
            int n = wc * (NI * 16) + ni * 16 + m16;
            int p = quad ^ swz(n);
            bfr[ni] = *reinterpret_cast<const short8*>(&Bs[n * 32 + p * 8]);
        }
#pragma unroll
        for (int mi = 0; mi < 4; mi++)
#pragma unroll
            for (int ni = 0; ni < NI; ni++)
                acc[mi][ni] = __builtin_amdgcn_mfma_f32_16x16x32_bf16(af[mi], bfr[ni], acc[mi][ni], 0, 0, 0);
        __syncthreads();
    }

    // epilogue: C/D layout col=lane&15, row=quad*4+reg
#pragma unroll
    for (int mi = 0; mi < 4; mi++) {
#pragma unroll
        for (int reg = 0; reg < 4; reg++) {
            int grow = row0 + wr * 64 + mi * 16 + quad * 4 + reg;
            if (grow >= nrows) continue;
#pragma unroll
            for (int ni = 0; ni < NI; ni++) {
                int gcol = col0 + wc * (NI * 16) + ni * 16 + m16;
                float v = acc[mi][ni][reg];
                if constexpr (BIASACT) {
                    v += bias[gcol];
                    v = (v > 0.f) ? v : NEG_SLOPE * v;
                }
                if constexpr (OUT_BF16) Cb[(size_t)grow * ldc + gcol] = f2bf(v);
                else                    Cf[(size_t)grow * ldc + gcol] = v;
            }
        }
    }
}

template<int BN, bool BIASACT, bool OUT_BF16>
__global__ __launch_bounds__(256) void mfma_gemm(
    const ushort_t* __restrict__ A, int lda,
    const ushort_t* __restrict__ Wt,
    const float* __restrict__ bias,
    float* __restrict__ Cf, ushort_t* __restrict__ Cb, int ldc,
    int nrows, int K)
{
    __shared__ ushort_t As[128 * 32];
    __shared__ ushort_t Bs[BN * 32];
    gemm_body<BN, BIASACT, OUT_BF16>(As, Bs, A, lda, Wt, bias, Cf, Cb, ldc, nrows, K,
                                     blockIdx.y * 128, blockIdx.x * BN);
}

// z-batched dual GEMM (both GCN chains in one launch), BN=64, no bias, bf16 out
__global__ __launch_bounds__(256) void mfma_gemm_dual(
    const ushort_t* __restrict__ A0, const ushort_t* __restrict__ A1, int lda,
    const ushort_t* __restrict__ W0, const ushort_t* __restrict__ W1,
    ushort_t* __restrict__ C0, ushort_t* __restrict__ C1, int ldc,
    int nrows, int K)
{
    __shared__ ushort_t As[128 * 32];
    __shared__ ushort_t Bs[64 * 32];
    const ushort_t* A  = blockIdx.z ? A1 : A0;
    const ushort_t* Wt = blockIdx.z ? W1 : W0;
    ushort_t*       Cb = blockIdx.z ? C1 : C0;
    gemm_body<64, false, true>(As, Bs, A, lda, Wt, nullptr, nullptr, Cb, ldc, nrows, K,
                               blockIdx.y * 128, blockIdx.x * 64);
}

// ---------------- GCN aggregation: wave per (node, chain, half) ----------------
// 80000 waves, slice-major (slice = chain*2+half) so concurrent waves gather
// from the same 2.56 MB L2-resident table slice. Lane = 32 feature-pairs x 2
// edge-sublanes. csr_pk.x is a premultiplied byte offset (src*256), so the
// gather address is one 32-bit add onto an SGPR base. f32x2 accumulators ->
// packed v_pk_fma_f32. No block barriers, no LDS reduction.
__global__ __launch_bounds__(256) void aggregate_wave(
    const ushort_t* __restrict__ tabA, const ushort_t* __restrict__ tabB,
    const float* __restrict__ bc, const float* __restrict__ bo,
    const int* __restrict__ ofs, const uint2* __restrict__ csr_pk,
    const float* __restrict__ deg_inv,
    ushort_t* __restrict__ outb, int hcol, int gcol)
{
    __shared__ uint2 s_pk[4][64];
    const int w = threadIdx.x >> 6, lane = threadIdx.x & 63;
    const int task = blockIdx.x * 4 + w;
    const int slice = task / NN;                 // 0..3 = (chain<<1)|half
    const int i = task - slice * NN;
    const int chain = slice >> 1, half = slice & 1;
    const char* __restrict__ tabc = (const char*)(chain ? tabB : tabA);
    const float* __restrict__ bias = chain ? bo : bc;
    const int el = lane >> 5;                    // edge sublane 0/1
    const int fl = lane & 31;                    // feature-pair index
    const int coloff = half * 64 + fl * 2;
    const unsigned lbyte = (unsigned)(coloff * 2);  // byte offset within table row

    const int start = ofs[i], end = ofs[i + 1];
    f32x2 acc = {0.f, 0.f};

    for (int base = start; base < end; base += 64) {
        int n = end - base; if (n > 64) n = 64;
        if (lane < n) s_pk[w][lane] = csr_pk[base + lane];
        // wave-synchronous: LDS ops from one wave are in-order; no barrier needed
        int j = el;
        for (; j + 6 < n; j += 8) {
            uint2 ea = s_pk[w][j],     eb = s_pk[w][j + 2];
            uint2 ec = s_pk[w][j + 4], ed = s_pk[w][j + 6];
            unsigned pa = *reinterpret_cast<const unsigned*>(tabc + (ea.x + lbyte));
            unsigned pb = *reinterpret_cast<const unsigned*>(tabc + (eb.x + lbyte));
            unsigned pc = *reinterpret_cast<const unsigned*>(tabc + (ec.x + lbyte));
            unsigned pd = *reinterpret_cast<const unsigned*>(tabc + (ed.x + lbyte));
            float ca = __uint_as_float(ea.y), cb = __uint_as_float(eb.y);
            float cc = __uint_as_float(ec.y), cd = __uint_as_float(ed.y);
            f32x2 va = {bflo(pa), bfhi(pa)}, vb = {bflo(pb), bfhi(pb)};
            f32x2 vc = {bflo(pc), bfhi(pc)}, vd = {bflo(pd), bfhi(pd)};
            acc += va * (f32x2){ca, ca};
            acc += vb * (f32x2){cb, cb};
            acc += vc * (f32x2){cc, cc};
            acc += vd * (f32x2){cd, cd};
        }
        for (; j < n; j += 2) {
            uint2 ee = s_pk[w][j];
            unsigned pv = *reinterpret_cast<const unsigned*>(tabc + (ee.x + lbyte));
            float cf = __uint_as_float(ee.y);
            f32x2 v = {bflo(pv), bfhi(pv)};
            acc += v * (f32x2){cf, cf};
        }
    }
    float a0 = acc.x + __shfl_xor(acc.x, 32);
    float a1 = acc.y + __shfl_xor(acc.y, 32);
    if (el == 0) {
        float di = deg_inv[i];
        float c = 2.f * di * di;
        unsigned pv = *reinterpret_cast<const unsigned*>(tabc + ((unsigned)i * 256u + lbyte));
        a0 = fmaf(bflo(pv), c, a0);
        a1 = fmaf(bfhi(pv), c, a1);
        a0 += bias[coloff];
        a1 += bias[coloff + 1];
        a0 = (a0 > 0.f) ? a0 : NEG_SLOPE * a0;
        a1 = (a1 > 0.f) ? a1 : NEG_SLOPE * a1;
        int col = (chain ? gcol : hcol) + coloff;
        unsigned o = (unsigned)f2bf(a0) | ((unsigned)f2bf(a1) << 16);
        *reinterpret_cast<unsigned*>(&outb[(size_t)i * 768 + col]) = o;
    }
}

// ---------------- final 2-wide heads: wave per node ----------------
__global__ __launch_bounds__(256) void heads_kernel(
    const float* __restrict__ tmpH,
    const float* __restrict__ Wod, const float* __restrict__ bod,
    const float* __restrict__ Wos, const float* __restrict__ bos,
    float* __restrict__ out)
{
    int w = threadIdx.x >> 6, lane = threadIdx.x & 63;
    int i = blockIdx.x * 4 + w;
    if (i >= NN) return;
    float a0 = 0.f, a1 = 0.f, d0 = 0.f, d1 = 0.f;
#pragma unroll
    for (int p = 0; p < 2; p++) {
        int k = lane + p * 64;
        float vd = tmpH[(size_t)i * 256 + k];
        float vs = tmpH[(size_t)i * 256 + 128 + k];
        a0 = fmaf(vd, Wod[k * 2 + 0], a0);
        a1 = fmaf(vd, Wod[k * 2 + 1], a1);
        d0 = fmaf(vs, Wos[k * 2 + 0], d0);
        d1 = fmaf(vs, Wos[k * 2 + 1], d1);
    }
    for (int off = 32; off; off >>= 1) {
        a0 += __shfl_down(a0, off);
        a1 += __shfl_down(a1, off);
        d0 += __shfl_down(d0, off);
        d1 += __shfl_down(d1, off);
    }
    if (lane == 0) {
        out[(size_t)i * 4 + 0] = a0 + bod[0];
        out[(size_t)i * 4 + 1] = a1 + bod[1];
        out[(size_t)i * 4 + 2] = d0 + bos[0];
        out[(size_t)i * 4 + 3] = d1 + bos[1];
    }
}

// ---------------- launch ----------------
extern "C" void kernel_launch(void* const* d_in, const int* in_sizes, int n_in,
                              void* d_out, int out_size, void* d_ws, size_t ws_size,
                              hipStream_t stream)
{
    const float* x      = (const float*)d_in[0];
    const float* x_ft   = (const float*)d_in[1];
    const int*   eidx   = (const int*)d_in[2];
    const float* W_pe   = (const float*)d_in[3];
    const float* b_pe   = (const float*)d_in[4];
    const float* W_gos  = (const float*)d_in[5];
    const float* b_gos  = (const float*)d_in[6];
    const float* W_prot = (const float*)d_in[7];
    const float* b_prot = (const float*)d_in[8];
    const float* W_om0  = (const float*)d_in[9];
    const float* b_om0  = (const float*)d_in[10];
    const float* W_om1  = (const float*)d_in[11];
    const float* b_om1  = (const float*)d_in[12];
    const float* W_om2  = (const float*)d_in[13];
    const float* b_om2  = (const float*)d_in[14];
    const float* W_om3  = (const float*)d_in[15];
    const float* b_om3  = (const float*)d_in[16];
    const float* W_c[3] = {(const float*)d_in[17], (const float*)d_in[21], (const float*)d_in[25]};
    const float* b_c[3] = {(const float*)d_in[18], (const float*)d_in[22], (const float*)d_in[26]};
    const float* W_o[3] = {(const float*)d_in[19], (const float*)d_in[23], (const float*)d_in[27]};
    const float* b_o[3] = {(const float*)d_in[20], (const float*)d_in[24], (const float*)d_in[28]};
    const float* W_lat  = (const float*)d_in[29];
    const float* b_lat  = (const float*)d_in[30];
    const float* W_drug = (const float*)d_in[31];
    const float* b_drug = (const float*)d_in[32];
    const float* W_dis  = (const float*)d_in[33];
    const float* b_dis  = (const float*)d_in[34];
    const float* W_odrug= (const float*)d_in[35];
    const float* b_odrug= (const float*)d_in[36];
    const float* W_odis = (const float*)d_in[37];
    const float* b_odis = (const float*)d_in[38];
    float* out = (float*)d_out;

    const int* e_src = eidx;
    const int* e_dst = eidx + NE;

    char* p = (char*)d_ws;
    auto alloc = [&](size_t bytes) -> void* {
        void* r = (void*)p;
        p += (bytes + 255) & ~(size_t)255;
        return r;
    };
    ushort_t* Wt    = (ushort_t*)alloc((size_t)WT_TOTAL * 2);
    float* bcat     = (float*)alloc(384 * 4);
    float* bomc     = (float*)alloc(384 * 4);
    float* bheads   = (float*)alloc(256 * 4);
    float* deg_inv  = (float*)alloc((size_t)NN * 4);
    int*   cnt      = (int*)alloc((size_t)NN * 4);
    int*   ofs      = (int*)alloc((size_t)(NN + 1) * 4);
    int*   cursor   = (int*)alloc((size_t)NN * 4);
    int*   bsum     = (int*)alloc((size_t)NSCAN * 4);
    int*   boff     = (int*)alloc((size_t)NSCAN * 4);
    uint2* csr_pk   = (uint2*)alloc((size_t)NE * 8);
    ushort_t* xb    = (ushort_t*)alloc((size_t)NNP * 736 * 2);
    ushort_t* xftb  = (ushort_t*)alloc((size_t)NNP * 64 * 2);
    ushort_t* h0b   = (ushort_t*)alloc((size_t)NNP * 384 * 2);
    ushort_t* g0b   = (ushort_t*)alloc((size_t)NNP * 384 * 2);
    ushort_t* jkb   = (ushort_t*)alloc((size_t)NNP * 768 * 2);
    ushort_t* zb    = (ushort_t*)alloc((size_t)NNP * 384 * 2);
    ushort_t* tmpAb = (ushort_t*)alloc((size_t)NNP * 128 * 2);
    ushort_t* tmpBb = (ushort_t*)alloc((size_t)NNP * 128 * 2);
    float* tmpH     = (float*)alloc((size_t)NNP * 256 * 4);
    (void)ws_size; (void)in_sizes; (void)n_in; (void)out_size;

    // 1. pack + transpose weights to bf16 [M][K]
    {
        int total = WT_TOTAL + 384 + 384 + 256;
        pack_weights<<<dim3((total + 255) / 256), dim3(256), 0, stream>>>(
            W_pe, W_gos, W_prot, b_pe, b_gos, b_prot,
            W_om0, W_om1, W_om2, W_om3, b_om0, b_om1, b_om2, b_om3,
            W_c[0], W_o[0], W_c[1], W_o[1], W_c[2], W_o[2],
            W_lat, W_drug, W_dis, b_drug, b_dis, Wt, bcat, bomc, bheads);
    }
    // 2. convert inputs to bf16 (fused)
    convert_inputs<<<dim3((CVT_T1 + NN * 64 + 255) / 256), dim3(256), 0, stream>>>(x, x_ft, xb, xftb);

    // 3. degree + CSR (sliced atomics, hierarchical scan, packed fill)
    hipMemsetAsync(cnt, 0, (size_t)NN * 4, stream);
    count_deg_sliced<<<dim3(NSL * FBPS), dim3(256), 0, stream>>>(e_dst, cnt);
    scan_blocksums<<<dim3(NSCAN), dim3(256), 0, stream>>>(cnt, bsum, deg_inv);
    scan_tops<<<dim3(1), dim3(128), 0, stream>>>(bsum, boff, ofs);
    scan_apply<<<dim3(NSCAN), dim3(256), 0, stream>>>(cnt, boff, ofs, cursor);
    fill_csr_sliced<<<dim3(NSL * FBPS), dim3(256), 0, stream>>>(e_src, e_dst, deg_inv, cursor, csr_pk);

    // 4. input MLPs (bf16 MFMA, bf16 out)
    mfma_gemm<128, true, true><<<dim3(3, 157), dim3(256), 0, stream>>>(
        xb, 736, Wt + O_CAT, bcat, nullptr, h0b, 384, NN, 736);
    mfma_gemm<128, true, true><<<dim3(3, 157), dim3(256), 0, stream>>>(
        xftb, 64, Wt + O_OM, bomc, nullptr, g0b, 384, NN, 64);

    // 5. three GCN layers. jkb = bf16 [h1 h2 h3 g1 g2 g3], stride 768
    mfma_gemm_dual<<<dim3(2, 157, 2), dim3(256), 0, stream>>>(
        h0b, g0b, 384, Wt + O_C0, Wt + O_O0, tmpAb, tmpBb, 128, NN, 384);
    aggregate_wave<<<dim3(NN), dim3(256), 0, stream>>>(
        tmpAb, tmpBb, b_c[0], b_o[0], ofs, csr_pk, deg_inv, jkb, 0, 384);

    mfma_gemm_dual<<<dim3(2, 157, 2), dim3(256), 0, stream>>>(
        jkb + 0, jkb + 384, 768, Wt + O_C1, Wt + O_O1, tmpAb, tmpBb, 128, NN, 128);
    aggregate_wave<<<dim3(NN), dim3(256), 0, stream>>>(
        tmpAb, tmpBb, b_c[1], b_o[1], ofs, csr_pk, deg_inv, jkb, 128, 512);

    mfma_gemm_dual<<<dim3(2, 157, 2), dim3(256), 0, stream>>>(
        jkb + 128, jkb + 512, 768, Wt + O_C2, Wt + O_O2, tmpAb, tmpBb, 128, NN, 128);
    aggregate_wave<<<dim3(NN), dim3(256), 0, stream>>>(
        tmpAb, tmpBb, b_c[2], b_o[2], ofs, csr_pk, deg_inv, jkb, 256, 640);

    // 6. latent: zb = act(jkb @ W_lat + b_lat), bf16
    mfma_gemm<128, true, true><<<dim3(3, 157), dim3(256), 0, stream>>>(
        jkb, 768, Wt + O_LAT, b_lat, nullptr, zb, 384, NN, 768);

    // 7. fused heads GEMM (M=256): tmpH = act(zb @ [Wd|Ws] + [bd|bs]), fp32
    mfma_gemm<128, true, false><<<dim3(2, 157), dim3(256), 0, stream>>>(
        zb, 384, Wt + O_HEADS, bheads, tmpH, nullptr, 256, NN, 384);
    heads_kernel<<<dim3((NN + 3) / 4), dim3(256), 0, stream>>>(
        tmpH, W_odrug, b_odrug, W_odis, b_odis, out);
}

// Round 7
// 499.737 us; speedup vs baseline: 1.0256x; 1.0256x over previous
//
#include <hip/hip_runtime.h>
#include <cstdint>

#define NN 20000
#define NNP 20096            // 157 * 128, padded row count for all activation buffers
#define NE 640000
#define NEG_SLOPE 0.1f
#define NSCAN 79             // ceil(NN/256)
#define NSL 8                // dst slices (XCD-count)
#define NPSL 2500            // nodes per slice
#define FBPS 160             // fill blocks per slice

typedef unsigned short ushort_t;
typedef __attribute__((ext_vector_type(8))) short short8;
typedef __attribute__((ext_vector_type(4))) float f32x4;
typedef __attribute__((ext_vector_type(2))) float f32x2;

__device__ __forceinline__ unsigned short f2bf(float f) {
    union { float f; unsigned u; } v; v.f = f;
    unsigned r = v.u + 0x7fffu + ((v.u >> 16) & 1u);
    return (unsigned short)(r >> 16);
}
__device__ __forceinline__ float bflo(unsigned u) { return __uint_as_float(u << 16); }
__device__ __forceinline__ float bfhi(unsigned u) { return __uint_as_float(u & 0xffff0000u); }

__device__ __forceinline__ int swz(int r) { return (r ^ (r >> 2)) & 3; }

__device__ __forceinline__ void gld_lds16(const void* g, void* l) {
    __builtin_amdgcn_global_load_lds(
        (const __attribute__((address_space(1))) void*)g,
        (__attribute__((address_space(3))) void*)l,
        16, 0, 0);
}

// ---------------- packed Wt region offsets (elements, bf16) ----------------
// All Wt stored as [M][K] row-major (transposed from source [K][M])
#define O_CAT   0            // 384 x 736
#define O_OM    282624       // 384 x 64 (K padded 54->64 with zeros)
#define O_C0    307200       // 128 x 384
#define O_O0    356352       // 128 x 384
#define O_C1    405504       // 128 x 128
#define O_O1    421888
#define O_C2    438272
#define O_O2    454656
#define O_LAT   471040       // 384 x 768
#define O_HEADS 765952       // 256 x 384  (rows 0..127 = drug, 128..255 = dis)
#define WT_TOTAL 864256

__global__ __launch_bounds__(256) void pack_weights(
    const float* __restrict__ Wpe, const float* __restrict__ Wgos, const float* __restrict__ Wprot,
    const float* __restrict__ bpe, const float* __restrict__ bgos, const float* __restrict__ bprot,
    const float* __restrict__ Wom0, const float* __restrict__ Wom1,
    const float* __restrict__ Wom2, const float* __restrict__ Wom3,
    const float* __restrict__ bom0, const float* __restrict__ bom1,
    const float* __restrict__ bom2, const float* __restrict__ bom3,
    const float* __restrict__ Wc0, const float* __restrict__ Wo0,
    const float* __restrict__ Wc1, const float* __restrict__ Wo1,
    const float* __restrict__ Wc2, const float* __restrict__ Wo2,
    const float* __restrict__ Wlat,
    const float* __restrict__ Wdrug, const float* __restrict__ Wdis,
    const float* __restrict__ bdrug, const float* __restrict__ bdis,
    ushort_t* __restrict__ Wt, float* __restrict__ bcat, float* __restrict__ bomc,
    float* __restrict__ bheads)
{
    int i = blockIdx.x * blockDim.x + threadIdx.x;
    if (i < 282624) {                            // WtCat 384 x 736
        int m = i / 736, k = i % 736;
        float v = (k < 128) ? Wpe[k * 384 + m]
                : (k < 256) ? Wgos[(k - 128) * 384 + m]
                            : Wprot[(k - 256) * 384 + m];
        Wt[O_CAT + i] = f2bf(v);
        return;
    }
    i -= 282624;
    if (i < 24576) {                             // WtOm 384 x 64
        int m = i / 64, k = i % 64;
        float v = (k < 3)  ? Wom0[k * 384 + m]
                : (k < 6)  ? Wom1[(k - 3) * 384 + m]
                : (k < 30) ? Wom2[(k - 6) * 384 + m]
                : (k < 54) ? Wom3[(k - 30) * 384 + m] : 0.f;
        Wt[O_OM + i] = f2bf(v);
        return;
    }
    i -= 24576;
    if (i < 49152) { int m = i / 384, k = i % 384; Wt[O_C0 + i] = f2bf(Wc0[k * 128 + m]); return; }
    i -= 49152;
    if (i < 49152) { int m = i / 384, k = i % 384; Wt[O_O0 + i] = f2bf(Wo0[k * 128 + m]); return; }
    i -= 49152;
    if (i < 16384) { int m = i / 128, k = i % 128; Wt[O_C1 + i] = f2bf(Wc1[k * 128 + m]); return; }
    i -= 16384;
    if (i < 16384) { int m = i / 128, k = i % 128; Wt[O_O1 + i] = f2bf(Wo1[k * 128 + m]); return; }
    i -= 16384;
    if (i < 16384) { int m = i / 128, k = i % 128; Wt[O_C2 + i] = f2bf(Wc2[k * 128 + m]); return; }
    i -= 16384;
    if (i < 16384) { int m = i / 128, k = i % 128; Wt[O_O2 + i] = f2bf(Wo2[k * 128 + m]); return; }
    i -= 16384;
    if (i < 294912) { int m = i / 768, k = i % 768; Wt[O_LAT + i] = f2bf(Wlat[k * 384 + m]); return; }
    i -= 294912;
    if (i < 98304) {                             // heads 256 x 384
        int m = i / 384, k = i % 384;
        float v = (m < 128) ? Wdrug[k * 128 + m] : Wdis[k * 128 + (m - 128)];
        Wt[O_HEADS + i] = f2bf(v);
        return;
    }
    i -= 98304;
    if (i < 384) { bcat[i] = bpe[i] + bgos[i] + bprot[i]; return; }
    i -= 384;
    if (i < 384) { bomc[i] = bom0[i] + bom1[i] + bom2[i] + bom3[i]; return; }
    i -= 384;
    if (i < 256) { bheads[i] = (i < 128) ? bdrug[i] : bdis[i - 128]; return; }
}

// ---------------- fused input conversion ----------------
#define CVT_T1 (NN * 736 / 4)
__global__ __launch_bounds__(256) void convert_inputs(
    const float* __restrict__ x, const float* __restrict__ xft,
    ushort_t* __restrict__ xb, ushort_t* __restrict__ xftb)
{
    int i = blockIdx.x * blockDim.x + threadIdx.x;
    if (i < CVT_T1) {
        int base = i * 4;
        float4 v = *reinterpret_cast<const float4*>(&x[base]);
        unsigned long long p = (unsigned long long)f2bf(v.x)
                             | ((unsigned long long)f2bf(v.y) << 16)
                             | ((unsigned long long)f2bf(v.z) << 32)
                             | ((unsigned long long)f2bf(v.w) << 48);
        *reinterpret_cast<unsigned long long*>(&xb[base]) = p;
        return;
    }
    i -= CVT_T1;
    if (i < NN * 64) {
        int r = i >> 6, c = i & 63;
        float v = (c < 54) ? xft[r * 54 + c] : 0.f;
        xftb[i] = f2bf(v);
    }
}

// ---------------- degree / CSR (sliced: slice = blockIdx.x & 7 owns 2500 dsts) ----
__global__ __launch_bounds__(256) void count_deg_sliced(const int* __restrict__ dst, int* __restrict__ cnt)
{
    const int slice = blockIdx.x & (NSL - 1);
    const int blk = blockIdx.x >> 3;
    const int lo = slice * NPSL, hi = lo + NPSL;
    for (int e = blk * 256 + threadIdx.x; e < NE; e += FBPS * 256) {
        int d = dst[e];
        if (d >= lo && d < hi) atomicAdd(&cnt[d], 1);
    }
}

// hierarchical scan: per-block sums (+deg_inv) -> tiny top scan -> apply
__global__ __launch_bounds__(256) void scan_blocksums(const int* __restrict__ cnt, int* __restrict__ bsum,
                                                      float* __restrict__ deg_inv)
{
    __shared__ int s[256];
    int t = threadIdx.x, i = blockIdx.x * 256 + t;
    int v = (i < NN) ? cnt[i] : 0;
    if (i < NN) deg_inv[i] = rsqrtf((float)v + 2.0f);
    s[t] = v;
    __syncthreads();
    for (int off = 128; off; off >>= 1) {
        if (t < off) s[t] += s[t + off];
        __syncthreads();
    }
    if (t == 0) bsum[blockIdx.x] = s[0];
}

__global__ __launch_bounds__(128) void scan_tops(const int* __restrict__ bsum,
                                                 int* __restrict__ boff, int* __restrict__ ofs)
{
    __shared__ int s[NSCAN];
    int t = threadIdx.x;
    if (t < NSCAN) s[t] = bsum[t];
    __syncthreads();
    if (t == 0) {
        int run = 0;
        for (int b = 0; b < NSCAN; b++) { int x = s[b]; s[b] = run; run += x; }
        ofs[NN] = run;
    }
    __syncthreads();
    if (t < NSCAN) boff[t] = s[t];
}

__global__ __launch_bounds__(256) void scan_apply(const int* __restrict__ cnt, const int* __restrict__ boff,
                                                  int* __restrict__ ofs, int* __restrict__ cursor)
{
    __shared__ int s[256];
    int t = threadIdx.x, i = blockIdx.x * 256 + t;
    int v = (i < NN) ? cnt[i] : 0;
    s[t] = v;
    __syncthreads();
    for (int off = 1; off < 256; off <<= 1) {
        int u = (t >= off) ? s[t - off] : 0;
        __syncthreads();
        s[t] += u;
        __syncthreads();
    }
    int excl = s[t] - v + boff[blockIdx.x];
    if (i < NN) { ofs[i] = excl; cursor[i] = excl; }
}

// sliced fill: per-slice cursor atomics hit a 10 KB region; csr writes land in a
// contiguous ~640 KB per-slice region. Packed entry: x = src*256 (byte offset of
// the 128-feat bf16 table row), y = coefficient fp32 bits.
__global__ __launch_bounds__(256) void fill_csr_sliced(
    const int* __restrict__ src, const int* __restrict__ dst,
    const float* __restrict__ deg_inv, int* __restrict__ cursor,
    uint2* __restrict__ csr_pk)
{
    const int slice = blockIdx.x & (NSL - 1);
    const int blk = blockIdx.x >> 3;
    const int lo = slice * NPSL, hi = lo + NPSL;
    for (int e = blk * 256 + threadIdx.x; e < NE; e += FBPS * 256) {
        int d = dst[e];
        if (d >= lo && d < hi) {
            int s = src[e];
            int p = atomicAdd(&cursor[d], 1);
            float cf = deg_inv[s] * deg_inv[d];
            csr_pk[p] = make_uint2((unsigned)s * 256u, __float_as_uint(cf));
        }
    }
}

// ---------------- bf16 MFMA GEMM body ----------------
// C[nrows x M] = [act]( A(bf16, nrows x K, lda) @ Wt(bf16, [M][K])^T [+ bias] )
// BM=128, BK=32, 256 threads = 4 waves 2x2. A buffers must have >= gridDim.y*128 rows.
template<int BN, bool BIASACT, bool OUT_BF16>
__device__ __forceinline__ void gemm_body(
    ushort_t* As, ushort_t* Bs,
    const ushort_t* __restrict__ A, int lda,
    const ushort_t* __restrict__ Wt,
    const float* __restrict__ bias,
    float* __restrict__ Cf, ushort_t* __restrict__ Cb, int ldc,
    int nrows, int K, int row0, int col0)
{
    constexpr int BK = 32;
    constexpr int NI = (BN == 128) ? 4 : 2;

    const int t = threadIdx.x;
    const int w = t >> 6, lane = t & 63;
    const int wr = w >> 1, wc = w & 1;
    const int m16 = lane & 15, quad = lane >> 4;
    const int sr = lane >> 2;       // row within a 16-row staging chunk
    const int pgrp = lane & 3;      // physical 16B group within row

    f32x4 acc[4][NI];
#pragma unroll
    for (int mi = 0; mi < 4; mi++)
#pragma unroll
        for (int ni = 0; ni < NI; ni++) acc[mi][ni] = (f32x4)0.f;

    for (int k0 = 0; k0 < K; k0 += BK) {
#pragma unroll
        for (int p = 0; p < 2; p++) {
            int c = p * 4 + w;
            int r = c * 16 + sr;
            int q = pgrp ^ swz(r);
            gld_lds16(&A[(size_t)(row0 + r) * lda + k0 + q * 8], &As[c * 512]);
        }
#pragma unroll
        for (int p = 0; p < BN / 64; p++) {
            int c = p * 4 + w;
            int r = c * 16 + sr;
            int q = pgrp ^ swz(r);
            gld_lds16(&Wt[(size_t)(col0 + r) * K + k0 + q * 8], &Bs[c * 512]);
        }
        __syncthreads();

        short8 af[4], bfr[NI];
#pragma unroll
        for (int mi = 0; mi < 4; mi++) {
            int r = wr * 64 + mi * 16 + m16;
            int p = quad ^ swz(r);
            af[mi] = *reinterpret_cast<const short8*>(&As[r * 32 + p * 8]);
        }
#pragma unroll
        for (int ni = 0; ni < NI; ni++) {
            int n = wc * (NI * 16) + ni * 16 + m16;
            int p = quad ^ swz(n);
            bfr[ni] = *reinterpret_cast<const short8*>(&Bs[n * 32 + p * 8]);
        }
#pragma unroll
        for (int mi = 0; mi < 4; mi++)
#pragma unroll
            for (int ni = 0; ni < NI; ni++)
                acc[mi][ni] = __builtin_amdgcn_mfma_f32_16x16x32_bf16(af[mi], bfr[ni], acc[mi][ni], 0, 0, 0);
        __syncthreads();
    }

    // epilogue: C/D layout col=lane&15, row=quad*4+reg
#pragma unroll
    for (int mi = 0; mi < 4; mi++) {
#pragma unroll
        for (int reg = 0; reg < 4; reg++) {
            int grow = row0 + wr * 64 + mi * 16 + quad * 4 + reg;
            if (grow >= nrows) continue;
#pragma unroll
            for (int ni = 0; ni < NI; ni++) {
                int gcol = col0 + wc * (NI * 16) + ni * 16 + m16;
                float v = acc[mi][ni][reg];
                if constexpr (BIASACT) {
                    v += bias[gcol];
                    v = (v > 0.f) ? v : NEG_SLOPE * v;
                }
                if constexpr (OUT_BF16) Cb[(size_t)grow * ldc + gcol] = f2bf(v);
                else                    Cf[(size_t)grow * ldc + gcol] = v;
            }
        }
    }
}

template<int BN, bool BIASACT, bool OUT_BF16>
__global__ __launch_bounds__(256) void mfma_gemm(
    const ushort_t* __restrict__ A, int lda,
    const ushort_t* __restrict__ Wt,
    const float* __restrict__ bias,
    float* __restrict__ Cf, ushort_t* __restrict__ Cb, int ldc,
    int nrows, int K)
{
    __shared__ ushort_t As[128 * 32];
    __shared__ ushort_t Bs[BN * 32];
    gemm_body<BN, BIASACT, OUT_BF16>(As, Bs, A, lda, Wt, bias, Cf, Cb, ldc, nrows, K,
                                     blockIdx.y * 128, blockIdx.x * BN);
}

// z-batched dual GEMM (both GCN chains in one launch), BN=64, no bias, bf16 out
__global__ __launch_bounds__(256) void mfma_gemm_dual(
    const ushort_t* __restrict__ A0, const ushort_t* __restrict__ A1, int lda,
    const ushort_t* __restrict__ W0, const ushort_t* __restrict__ W1,
    ushort_t* __restrict__ C0, ushort_t* __restrict__ C1, int ldc,
    int nrows, int K)
{
    __shared__ ushort_t As[128 * 32];
    __shared__ ushort_t Bs[64 * 32];
    const ushort_t* A  = blockIdx.z ? A1 : A0;
    const ushort_t* Wt = blockIdx.z ? W1 : W0;
    ushort_t*       Cb = blockIdx.z ? C1 : C0;
    gemm_body<64, false, true>(As, Bs, A, lda, Wt, nullptr, nullptr, Cb, ldc, nrows, K,
                               blockIdx.y * 128, blockIdx.x * 64);
}

// ---------------- GCN aggregation: wave per (node, chain, half) ----------------
// 80000 waves, slice-major (slice = chain*2+half) so concurrent waves gather
// from the same 2.56 MB L2-resident table slice. Lane = 8 feature-16B-quads x
// 8 edge-sublanes: each lane gathers dwordx4 (16 B), so ONE wave vmem
// instruction covers 8 edges x 128 B; one ds_read_b64 covers 8 edges
// (sublane-broadcast, conflict-free). Hand-unrolled x2 for 2 outstanding
// gathers. Tail: 3 shfl_xor rounds over sublanes; el==0 lanes store the full
// half-row as dwordx4. No block barriers.
__global__ __launch_bounds__(256) void aggregate_wave(
    const ushort_t* __restrict__ tabA, const ushort_t* __restrict__ tabB,
    const float* __restrict__ bc, const float* __restrict__ bo,
    const int* __restrict__ ofs, const uint2* __restrict__ csr_pk,
    const float* __restrict__ deg_inv,
    ushort_t* __restrict__ outb, int hcol, int gcol)
{
    __shared__ uint2 s_pk[4][64];
    const int w = threadIdx.x >> 6, lane = threadIdx.x & 63;
    const int task = blockIdx.x * 4 + w;
    const int slice = task / NN;                 // 0..3 = (chain<<1)|half
    const int i = task - slice * NN;
    const int chain = slice >> 1, half = slice & 1;
    const char* __restrict__ tabc = (const char*)(chain ? tabB : tabA);
    const float* __restrict__ bias = chain ? bo : bc;
    const int el = lane >> 3;                    // edge sublane 0..7
    const int fq = lane & 7;                     // feature 16B-quad
    const unsigned lbyte = (unsigned)(half * 128 + fq * 16);

    const int start = ofs[i], end = ofs[i + 1];
    float acc[8];
#pragma unroll
    for (int q = 0; q < 8; q++) acc[q] = 0.f;

    for (int base = start; base < end; base += 64) {
        int n = end - base; if (n > 64) n = 64;
        if (lane < n) s_pk[w][lane] = csr_pk[base + lane];
        // wave-synchronous: same-wave LDS ops are in-order; no barrier needed
        int j = el;
        for (; j + 8 < n; j += 16) {
            uint2 e0 = s_pk[w][j];
            uint2 e1 = s_pk[w][j + 8];
            uint4 p0 = *reinterpret_cast<const uint4*>(tabc + (e0.x + lbyte));
            uint4 p1 = *reinterpret_cast<const uint4*>(tabc + (e1.x + lbyte));
            float c0 = __uint_as_float(e0.y), c1 = __uint_as_float(e1.y);
            acc[0] = fmaf(bflo(p0.x), c0, acc[0]); acc[1] = fmaf(bfhi(p0.x), c0, acc[1]);
            acc[2] = fmaf(bflo(p0.y), c0, acc[2]); acc[3] = fmaf(bfhi(p0.y), c0, acc[3]);
            acc[4] = fmaf(bflo(p0.z), c0, acc[4]); acc[5] = fmaf(bfhi(p0.z), c0, acc[5]);
            acc[6] = fmaf(bflo(p0.w), c0, acc[6]); acc[7] = fmaf(bfhi(p0.w), c0, acc[7]);
            acc[0] = fmaf(bflo(p1.x), c1, acc[0]); acc[1] = fmaf(bfhi(p1.x), c1, acc[1]);
            acc[2] = fmaf(bflo(p1.y), c1, acc[2]); acc[3] = fmaf(bfhi(p1.y), c1, acc[3]);
            acc[4] = fmaf(bflo(p1.z), c1, acc[4]); acc[5] = fmaf(bfhi(p1.z), c1, acc[5]);
            acc[6] = fmaf(bflo(p1.w), c1, acc[6]); acc[7] = fmaf(bfhi(p1.w), c1, acc[7]);
        }
        if (j < n) {
            uint2 e0 = s_pk[w][j];
            uint4 p0 = *reinterpret_cast<const uint4*>(tabc + (e0.x + lbyte));
            float c0 = __uint_as_float(e0.y);
            acc[0] = fmaf(bflo(p0.x), c0, acc[0]); acc[1] = fmaf(bfhi(p0.x), c0, acc[1]);
            acc[2] = fmaf(bflo(p0.y), c0, acc[2]); acc[3] = fmaf(bfhi(p0.y), c0, acc[3]);
            acc[4] = fmaf(bflo(p0.z), c0, acc[4]); acc[5] = fmaf(bfhi(p0.z), c0, acc[5]);
            acc[6] = fmaf(bflo(p0.w), c0, acc[6]); acc[7] = fmaf(bfhi(p0.w), c0, acc[7]);
        }
    }
    // reduce over the 8 edge-sublanes (lane bits 3..5)
#pragma unroll
    for (int m = 8; m <= 32; m <<= 1) {
#pragma unroll
        for (int q = 0; q < 8; q++) acc[q] += __shfl_xor(acc[q], m);
    }
    if (el == 0) {
        float di = deg_inv[i];
        float c = 2.f * di * di;
        uint4 pv = *reinterpret_cast<const uint4*>(tabc + ((unsigned)i * 256u + lbyte));
        float sv[8] = {bflo(pv.x), bfhi(pv.x), bflo(pv.y), bfhi(pv.y),
                       bflo(pv.z), bfhi(pv.z), bflo(pv.w), bfhi(pv.w)};
        const int coloff = half * 64 + fq * 8;
        uint4 o;
        unsigned* op = &o.x;
#pragma unroll
        for (int q = 0; q < 8; q += 2) {
            float v0 = fmaf(sv[q],     c, acc[q])     + bias[coloff + q];
            float v1 = fmaf(sv[q + 1], c, acc[q + 1]) + bias[coloff + q + 1];
            v0 = (v0 > 0.f) ? v0 : NEG_SLOPE * v0;
            v1 = (v1 > 0.f) ? v1 : NEG_SLOPE * v1;
            op[q >> 1] = (unsigned)f2bf(v0) | ((unsigned)f2bf(v1) << 16);
        }
        int col = (chain ? gcol : hcol) + coloff;
        *reinterpret_cast<uint4*>(&outb[(size_t)i * 768 + col]) = o;
    }
}

// ---------------- final 2-wide heads: wave per node ----------------
__global__ __launch_bounds__(256) void heads_kernel(
    const float* __restrict__ tmpH,
    const float* __restrict__ Wod, const float* __restrict__ bod,
    const float* __restrict__ Wos, const float* __restrict__ bos,
    float* __restrict__ out)
{
    int w = threadIdx.x >> 6, lane = threadIdx.x & 63;
    int i = blockIdx.x * 4 + w;
    if (i >= NN) return;
    float a0 = 0.f, a1 = 0.f, d0 = 0.f, d1 = 0.f;
#pragma unroll
    for (int p = 0; p < 2; p++) {
        int k = lane + p * 64;
        float vd = tmpH[(size_t)i * 256 + k];
        float vs = tmpH[(size_t)i * 256 + 128 + k];
        a0 = fmaf(vd, Wod[k * 2 + 0], a0);
        a1 = fmaf(vd, Wod[k * 2 + 1], a1);
        d0 = fmaf(vs, Wos[k * 2 + 0], d0);
        d1 = fmaf(vs, Wos[k * 2 + 1], d1);
    }
    for (int off = 32; off; off >>= 1) {
        a0 += __shfl_down(a0, off);
        a1 += __shfl_down(a1, off);
        d0 += __shfl_down(d0, off);
        d1 += __shfl_down(d1, off);
    }
    if (lane == 0) {
        out[(size_t)i * 4 + 0] = a0 + bod[0];
        out[(size_t)i * 4 + 1] = a1 + bod[1];
        out[(size_t)i * 4 + 2] = d0 + bos[0];
        out[(size_t)i * 4 + 3] = d1 + bos[1];
    }
}

// ---------------- launch ----------------
extern "C" void kernel_launch(void* const* d_in, const int* in_sizes, int n_in,
                              void* d_out, int out_size, void* d_ws, size_t ws_size,
                              hipStream_t stream)
{
    const float* x      = (const float*)d_in[0];
    const float* x_ft   = (const float*)d_in[1];
    const int*   eidx   = (const int*)d_in[2];
    const float* W_pe   = (const float*)d_in[3];
    const float* b_pe   = (const float*)d_in[4];
    const float* W_gos  = (const float*)d_in[5];
    const float* b_gos  = (const float*)d_in[6];
    const float* W_prot = (const float*)d_in[7];
    const float* b_prot = (const float*)d_in[8];
    const float* W_om0  = (const float*)d_in[9];
    const float* b_om0  = (const float*)d_in[10];
    const float* W_om1  = (const float*)d_in[11];
    const float* b_om1  = (const float*)d_in[12];
    const float* W_om2  = (const float*)d_in[13];
    const float* b_om2  = (const float*)d_in[14];
    const float* W_om3  = (const float*)d_in[15];
    const float* b_om3  = (const float*)d_in[16];
    const float* W_c[3] = {(const float*)d_in[17], (const float*)d_in[21], (const float*)d_in[25]};
    const float* b_c[3] = {(const float*)d_in[18], (const float*)d_in[22], (const float*)d_in[26]};
    const float* W_o[3] = {(const float*)d_in[19], (const float*)d_in[23], (const float*)d_in[27]};
    const float* b_o[3] = {(const float*)d_in[20], (const float*)d_in[24], (const float*)d_in[28]};
    const float* W_lat  = (const float*)d_in[29];
    const float* b_lat  = (const float*)d_in[30];
    const float* W_drug = (const float*)d_in[31];
    const float* b_drug = (const float*)d_in[32];
    const float* W_dis  = (const float*)d_in[33];
    const float* b_dis  = (const float*)d_in[34];
    const float* W_odrug= (const float*)d_in[35];
    const float* b_odrug= (const float*)d_in[36];
    const float* W_odis = (const float*)d_in[37];
    const float* b_odis = (const float*)d_in[38];
    float* out = (float*)d_out;

    const int* e_src = eidx;
    const int* e_dst = eidx + NE;

    char* p = (char*)d_ws;
    auto alloc = [&](size_t bytes) -> void* {
        void* r = (void*)p;
        p += (bytes + 255) & ~(size_t)255;
        return r;
    };
    ushort_t* Wt    = (ushort_t*)alloc((size_t)WT_TOTAL * 2);
    float* bcat     = (float*)alloc(384 * 4);
    float* bomc     = (float*)alloc(384 * 4);
    float* bheads   = (float*)alloc(256 * 4);
    float* deg_inv  = (float*)alloc((size_t)NN * 4);
    int*   cnt      = (int*)alloc((size_t)NN * 4);
    int*   ofs      = (int*)alloc((size_t)(NN + 1) * 4);
    int*   cursor   = (int*)alloc((size_t)NN * 4);
    int*   bsum     = (int*)alloc((size_t)NSCAN * 4);
    int*   boff     = (int*)alloc((size_t)NSCAN * 4);
    uint2* csr_pk   = (uint2*)alloc((size_t)NE * 8);
    ushort_t* xb    = (ushort_t*)alloc((size_t)NNP * 736 * 2);
    ushort_t* xftb  = (ushort_t*)alloc((size_t)NNP * 64 * 2);
    ushort_t* h0b   = (ushort_t*)alloc((size_t)NNP * 384 * 2);
    ushort_t* g0b   = (ushort_t*)alloc((size_t)NNP * 384 * 2);
    ushort_t* jkb   = (ushort_t*)alloc((size_t)NNP * 768 * 2);
    ushort_t* zb    = (ushort_t*)alloc((size_t)NNP * 384 * 2);
    ushort_t* tmpAb = (ushort_t*)alloc((size_t)NNP * 128 * 2);
    ushort_t* tmpBb = (ushort_t*)alloc((size_t)NNP * 128 * 2);
    float* tmpH     = (float*)alloc((size_t)NNP * 256 * 4);
    (void)ws_size; (void)in_sizes; (void)n_in; (void)out_size;

    // 1. pack + transpose weights to bf16 [M][K]
    {
        int total = WT_TOTAL + 384 + 384 + 256;
        pack_weights<<<dim3((total + 255) / 256), dim3(256), 0, stream>>>(
            W_pe, W_gos, W_prot, b_pe, b_gos, b_prot,
            W_om0, W_om1, W_om2, W_om3, b_om0, b_om1, b_om2, b_om3,
            W_c[0], W_o[0], W_c[1], W_o[1], W_c[2], W_o[2],
            W_lat, W_drug, W_dis, b_drug, b_dis, Wt, bcat, bomc, bheads);
    }
    // 2. convert inputs to bf16 (fused)
    convert_inputs<<<dim3((CVT_T1 + NN * 64 + 255) / 256), dim3(256), 0, stream>>>(x, x_ft, xb, xftb);

    // 3. degree + CSR (sliced atomics, hierarchical scan, packed fill)
    hipMemsetAsync(cnt, 0, (size_t)NN * 4, stream);
    count_deg_sliced<<<dim3(NSL * FBPS), dim3(256), 0, stream>>>(e_dst, cnt);
    scan_blocksums<<<dim3(NSCAN), dim3(256), 0, stream>>>(cnt, bsum, deg_inv);
    scan_tops<<<dim3(1), dim3(128), 0, stream>>>(bsum, boff, ofs);
    scan_apply<<<dim3(NSCAN), dim3(256), 0, stream>>>(cnt, boff, ofs, cursor);
    fill_csr_sliced<<<dim3(NSL * FBPS), dim3(256), 0, stream>>>(e_src, e_dst, deg_inv, cursor, csr_pk);

    // 4. input MLPs (bf16 MFMA, bf16 out)
    mfma_gemm<128, true, true><<<dim3(3, 157), dim3(256), 0, stream>>>(
        xb, 736, Wt + O_CAT, bcat, nullptr, h0b, 384, NN, 736);
    mfma_gemm<128, true, true><<<dim3(3, 157), dim3(256), 0, stream>>>(
        xftb, 64, Wt + O_OM, bomc, nullptr, g0b, 384, NN, 64);

    // 5. three GCN layers. jkb = bf16 [h1 h2 h3 g1 g2 g3], stride 768
    mfma_gemm_dual<<<dim3(2, 157, 2), dim3(256), 0, stream>>>(
        h0b, g0b, 384, Wt + O_C0, Wt + O_O0, tmpAb, tmpBb, 128, NN, 384);
    aggregate_wave<<<dim3(NN), dim3(256), 0, stream>>>(
        tmpAb, tmpBb, b_c[0], b_o[0], ofs, csr_pk, deg_inv, jkb, 0, 384);

    mfma_gemm_dual<<<dim3(2, 157, 2), dim3(256), 0, stream>>>(
        jkb + 0, jkb + 384, 768, Wt + O_C1, Wt + O_O1, tmpAb, tmpBb, 128, NN, 128);
    aggregate_wave<<<dim3(NN), dim3(256), 0, stream>>>(
        tmpAb, tmpBb, b_c[1], b_o[1], ofs, csr_pk, deg_inv, jkb, 128, 512);

    mfma_gemm_dual<<<dim3(2, 157, 2), dim3(256), 0, stream>>>(
        jkb + 128, jkb + 512, 768, Wt + O_C2, Wt + O_O2, tmpAb, tmpBb, 128, NN, 128);
    aggregate_wave<<<dim3(NN), dim3(256), 0, stream>>>(
        tmpAb, tmpBb, b_c[2], b_o[2], ofs, csr_pk, deg_inv, jkb, 256, 640);

    // 6. latent: zb = act(jkb @ W_lat + b_lat), bf16
    mfma_gemm<128, true, true><<<dim3(3, 157), dim3(256), 0, stream>>>(
        jkb, 768, Wt + O_LAT, b_lat, nullptr, zb, 384, NN, 768);

    // 7. fused heads GEMM (M=256): tmpH = act(zb @ [Wd|Ws] + [bd|bs]), fp32
    mfma_gemm<128, true, false><<<dim3(2, 157), dim3(256), 0, stream>>>(
        zb, 384, Wt + O_HEADS, bheads, tmpH, nullptr, 256, NN, 384);
    heads_kernel<<<dim3((NN + 3) / 4), dim3(256), 0, stream>>>(
        tmpH, W_odrug, b_odrug, W_odis, b_odis, out);
}